// Round 5
// baseline (120.748 us; speedup 1.0000x reference)
//
#include <hip/hip_runtime.h>

// MinimalAdderNN: base-10 ripple-carry adder -> one-hot logits [BATCH, 11, 10] f32.
// R5: R1-R4 all stored block-owned contiguous chunks (~56-112KB x 256 CUs) and
// all hit ~4.8 TB/s; fillBufferAligned (grid-stride, device-wide sliding
// window) hits 6.8 TB/s. Theory: chunked streams thrash DRAM row buffers.
// Fix: kernel B is a flat grid-stride float4 store loop (fill-shaped stream),
// digits read from an 8MB packed workspace (L2/LLC-hot).

#define THREADS 256
#define FPR 110  // floats per row: 11 positions * 10 slots

__device__ __forceinline__ void compute_pack(const int* __restrict__ ap,
                                             const int* __restrict__ bp,
                                             unsigned& w0, unsigned& w1) {
    int av[10], bv[10];
    const int2* ap2 = (const int2*)ap;  // rows are 40 B -> 8 B aligned
    const int2* bp2 = (const int2*)bp;
#pragma unroll
    for (int i = 0; i < 5; ++i) {
        int2 va = ap2[i]; av[2*i] = va.x; av[2*i+1] = va.y;
        int2 vb = bp2[i]; bv[2*i] = vb.x; bv[2*i+1] = vb.y;
    }
    int dig[11];
    int carry = 0;
#pragma unroll
    for (int p = 9; p >= 0; --p) {  // LSD first (memory is MSD-first)
        int tot = av[p] + bv[p] + carry;
        int c = tot >= 10;
        dig[1 + p] = c ? tot - 10 : tot;
        carry = c;
    }
    dig[0] = carry;  // leading one-hot position = final carry
    w0 = 0; w1 = 0;
#pragma unroll
    for (int pos = 0; pos < 8; ++pos) w0 |= (unsigned)dig[pos] << (4 * pos);
#pragma unroll
    for (int pos = 8; pos < 11; ++pos) w1 |= (unsigned)dig[pos] << (4 * (pos - 8));
}

// ---- Kernel A: read-dominated. a,b -> packed digits in workspace ----
__global__ __launch_bounds__(THREADS) void adder_pack_kernel(
    const int* __restrict__ a, const int* __restrict__ b,
    uint2* __restrict__ ws, int batch) {
    int r = blockIdx.x * THREADS + threadIdx.x;
    if (r >= batch) return;
    unsigned w0, w1;
    compute_pack(a + (size_t)r * 10, b + (size_t)r * 10, w0, w1);
    ws[r] = make_uint2(w0, w1);  // coalesced 8 B/lane
}

// ---- Kernel B: fill-shaped grid-stride write stream ----
__global__ __launch_bounds__(THREADS) void adder_store_kernel(
    const uint2* __restrict__ ws, float* __restrict__ out, int nvec) {
    // nvec = batch*110/4; ws has batch+1 entries (last one never selected,
    // only speculatively loaded).
    const int stride = gridDim.x * THREADS;
    float4* __restrict__ out4 = (float4*)out;

    for (int g = blockIdx.x * THREADS + threadIdx.x; g < nvec; g += stride) {
        unsigned e = 4u * (unsigned)g;
        unsigned row = e / 110u;            // compiler magic-mul
        unsigned rem = e - row * 110u;
        uint2 p0 = ws[row];
        uint2 p1 = ws[row + 1];             // speculative; padded allocation
        float4 v;
        float* vp = &v.x;
#pragma unroll
        for (int k = 0; k < 4; ++k) {
            unsigned re = rem + k;
            bool wrap = re >= 110u;
            unsigned re2 = wrap ? re - 110u : re;
            unsigned wlo = wrap ? p1.x : p0.x;
            unsigned whi = wrap ? p1.y : p0.y;
            unsigned pos = (re2 * 205u) >> 11;   // re2/10 for 0..109
            unsigned slot = re2 - 10u * pos;
            unsigned w = (pos >= 8u) ? whi : wlo;
            unsigned digit = (w >> ((pos & 7u) * 4u)) & 15u;
            vp[k] = (digit == slot) ? 1.0f : 0.0f;
        }
        out4[g] = v;
    }
}

// ---- Fallback: fused single-kernel (R3 form) if workspace is too small ----
#define FROWS 128
__global__ __launch_bounds__(THREADS) void adder_fused_kernel(
    const int* __restrict__ a, const int* __restrict__ b,
    float* __restrict__ out, int batch) {
    __shared__ uint2 packed[FROWS + 1];
    const int t = threadIdx.x;
    const int row0 = blockIdx.x * FROWS;

    if (t < FROWS) {
        if (row0 + t < batch) {
            unsigned w0, w1;
            compute_pack(a + (size_t)(row0 + t) * 10, b + (size_t)(row0 + t) * 10, w0, w1);
            packed[t] = make_uint2(w0, w1);
        } else {
            packed[t] = make_uint2(0u, 0u);
        }
    }
    if (t == 0) packed[FROWS] = make_uint2(0u, 0u);
    __syncthreads();

    const int rows_here = min(FROWS, batch - row0);
    const int total_f = rows_here * FPR;
    const int nvec = total_f >> 2;
    float4* out4 = (float4*)(out + (size_t)row0 * FPR);

    int e0 = 4 * t;
    int row = e0 / 110;
    int rem = e0 - 110 * row;
    for (int i = t; i < nvec; i += THREADS) {
        uint2 p0 = packed[row];
        uint2 p1 = packed[row + 1];
        float4 v;
        float* vp = &v.x;
#pragma unroll
        for (int k = 0; k < 4; ++k) {
            int re = rem + k;
            bool wrap = re >= 110;
            int re2 = wrap ? re - 110 : re;
            unsigned wlo = wrap ? p1.x : p0.x;
            unsigned whi = wrap ? p1.y : p0.y;
            int pos = (re2 * 205) >> 11;
            int slot = re2 - 10 * pos;
            unsigned w = (pos >= 8) ? whi : wlo;
            int digit = (w >> ((pos & 7) * 4)) & 15;
            vp[k] = (digit == slot) ? 1.0f : 0.0f;
        }
        out4[i] = v;
        row += 9;
        rem += 34;
        if (rem >= 110) { rem -= 110; ++row; }
    }
}

extern "C" void kernel_launch(void* const* d_in, const int* in_sizes, int n_in,
                              void* d_out, int out_size, void* d_ws, size_t ws_size,
                              hipStream_t stream) {
    const int* a = (const int*)d_in[0];
    const int* b = (const int*)d_in[1];
    // d_in[2]/d_in[3] (lookup tables) are deterministic -> replaced by arithmetic.
    float* out = (float*)d_out;
    const int batch = in_sizes[0] / 10;

    const size_t need = ((size_t)batch + 1) * sizeof(uint2);
    if (ws_size >= need) {
        const int gridA = (batch + THREADS - 1) / THREADS;
        adder_pack_kernel<<<gridA, THREADS, 0, stream>>>(a, b, (uint2*)d_ws, batch);

        const int nvec = (int)(((long long)batch * FPR) >> 2);  // batch*110 divisible by 4 here
        int gridB = 2048;  // ~8 blocks/CU; grid-stride covers the rest
        adder_store_kernel<<<gridB, THREADS, 0, stream>>>((const uint2*)d_ws, out, nvec);

        // Handle a ragged tail (batch*110 % 4 != 0) — impossible for batch=2^20,
        // but keep correctness for generality via the fused kernel on last rows.
        if (((long long)batch * FPR) & 3) {
            // Fall back entirely (simplest correct path).
            const int gridF = (batch + FROWS - 1) / FROWS;
            adder_fused_kernel<<<gridF, THREADS, 0, stream>>>(a, b, out, batch);
        }
    } else {
        const int gridF = (batch + FROWS - 1) / FROWS;
        adder_fused_kernel<<<gridF, THREADS, 0, stream>>>(a, b, out, batch);
    }
}

// Round 7
// 114.054 us; speedup vs baseline: 1.0587x; 1.0587x over previous
//
#include <hip/hip_runtime.h>

// MinimalAdderNN: base-10 ripple-carry adder -> one-hot logits [BATCH, 11, 10] f32.
// R6b: same as R6 (nontemporal stores to bypass L2 write-allocate on the
// 461 MB output stream; nontemporal loads for touch-once inputs) with
// compile fix: nontemporal builtins need native/ext_vector types, not
// HIP_vector_type wrappers. Structure = R3 fused best-known.

#define FROWS 128
#define THREADS 256
#define FPR 110  // floats per row: 11 positions * 10 slots

typedef float f32x4 __attribute__((ext_vector_type(4)));

__global__ __launch_bounds__(THREADS) void adder_fused_nt_kernel(
    const int* __restrict__ a, const int* __restrict__ b,
    float* __restrict__ out, int batch) {
    __shared__ uint2 packed[FROWS + 1];
    const int t = threadIdx.x;
    const int row0 = blockIdx.x * FROWS;

    // ---- Phase 1: threads 0..127 compute + nibble-pack their row ----
    if (t < FROWS) {
        uint2 pw = make_uint2(0u, 0u);
        if (row0 + t < batch) {
            const long long* ap2 = (const long long*)(a + (size_t)(row0 + t) * 10);
            const long long* bp2 = (const long long*)(b + (size_t)(row0 + t) * 10);
            int av[10], bv[10];
#pragma unroll
            for (int i = 0; i < 5; ++i) {
                long long va = __builtin_nontemporal_load(ap2 + i);
                long long vb = __builtin_nontemporal_load(bp2 + i);
                av[2*i]   = (int)(va & 0xffffffffLL); av[2*i+1] = (int)(va >> 32);
                bv[2*i]   = (int)(vb & 0xffffffffLL); bv[2*i+1] = (int)(vb >> 32);
            }
            int dig[11];
            int carry = 0;
#pragma unroll
            for (int p = 9; p >= 0; --p) {  // LSD first (memory is MSD-first)
                int tot = av[p] + bv[p] + carry;
                int c = tot >= 10;
                dig[1 + p] = c ? tot - 10 : tot;
                carry = c;
            }
            dig[0] = carry;  // leading one-hot position = final carry
            unsigned w0 = 0, w1 = 0;
#pragma unroll
            for (int pos = 0; pos < 8; ++pos) w0 |= (unsigned)dig[pos] << (4 * pos);
#pragma unroll
            for (int pos = 8; pos < 11; ++pos) w1 |= (unsigned)dig[pos] << (4 * (pos - 8));
            pw = make_uint2(w0, w1);
        }
        packed[t] = pw;
    }
    if (t == 0) packed[FROWS] = make_uint2(0u, 0u);
    __syncthreads();

    // ---- Phase 2: coalesced nontemporal float4 store stream ----
    const int rows_here = min(FROWS, batch - row0);
    const int total_f = rows_here * FPR;
    const int nvec = total_f >> 2;
    f32x4* out4 = (f32x4*)(out + (size_t)row0 * FPR);  // 128*440B base -> 16B aligned

    // Incremental divmod: e = 4*i; step e += 1024 = 9*110 + 34.
    int e0 = 4 * t;
    int row = e0 / 110;
    int rem = e0 - 110 * row;

    for (int i = t; i < nvec; i += THREADS) {
        uint2 p0 = packed[row];
        uint2 p1 = packed[row + 1];  // speculative; pad keeps it in-bounds
        f32x4 v;
#pragma unroll
        for (int k = 0; k < 4; ++k) {
            int re = rem + k;
            bool wrap = re >= 110;
            int re2 = wrap ? re - 110 : re;
            unsigned wlo = wrap ? p1.x : p0.x;
            unsigned whi = wrap ? p1.y : p0.y;
            int pos = (re2 * 205) >> 11;  // re2/10 for 0..109
            int slot = re2 - 10 * pos;
            unsigned w = (pos >= 8) ? whi : wlo;
            int digit = (w >> ((pos & 7) * 4)) & 15;
            v[k] = (digit == slot) ? 1.0f : 0.0f;
        }
        __builtin_nontemporal_store(v, out4 + i);

        row += 9;
        rem += 34;
        if (rem >= 110) { rem -= 110; ++row; }
    }

    // Scalar tail (none for batch=2^20), kept for generality.
    const int tail0 = nvec * 4;
    if (t < total_f - tail0) {
        int e = tail0 + t;
        int r = e / 110;
        int re2 = e - 110 * r;
        int pos = (re2 * 205) >> 11;
        int slot = re2 - 10 * pos;
        uint2 pw = packed[r];
        unsigned w = (pos >= 8) ? pw.y : pw.x;
        int digit = (w >> ((pos & 7) * 4)) & 15;
        out[(size_t)row0 * FPR + e] = (digit == slot) ? 1.0f : 0.0f;
    }
}

extern "C" void kernel_launch(void* const* d_in, const int* in_sizes, int n_in,
                              void* d_out, int out_size, void* d_ws, size_t ws_size,
                              hipStream_t stream) {
    const int* a = (const int*)d_in[0];
    const int* b = (const int*)d_in[1];
    // d_in[2]/d_in[3] (lookup tables) are deterministic -> replaced by arithmetic.
    float* out = (float*)d_out;
    const int batch = in_sizes[0] / 10;

    const int grid = (batch + FROWS - 1) / FROWS;
    adder_fused_nt_kernel<<<grid, THREADS, 0, stream>>>(a, b, out, batch);
}